// Round 15
// baseline (80.885 us; speedup 1.0000x reference)
//
#include <hip/hip_runtime.h>

typedef unsigned short ushort_t;
typedef __attribute__((ext_vector_type(8))) short bf16x8;
typedef __attribute__((ext_vector_type(8))) unsigned short ushort8;
typedef __attribute__((ext_vector_type(4))) float f32x4;

__device__ __forceinline__ unsigned short f2bf(float f) {
  union { float f; unsigned u; } x; x.f = f;
  unsigned r = x.u + 0x7FFFu + ((x.u >> 16) & 1u);   // round-to-nearest-even
  return (unsigned short)(r >> 16);
}

// ---------------- fused chain: block = one o (512 blocks x 256 thr)
__global__ __launch_bounds__(256) void chain_kernel(const float* __restrict__ f0,
                                                    const float* __restrict__ f1,
                                                    const float* __restrict__ lf,
                                                    ushort_t* __restrict__ chainT) {
  __shared__ float gs[512];
  int o = blockIdx.x;
  int z = o & 7, y = (o >> 3) & 7, x = o >> 6;
  int tid = threadIdx.x;
  #pragma unroll
  for (int i = 0; i < 2; ++i) {
    int e = tid + i * 256;                 // (b*16+q)*4+c
    int c = e & 3, q = (e >> 2) & 15, b = e >> 6;
    float s = 0.f;
    #pragma unroll
    for (int r = 0; r < 16; ++r)
      s += f1[((b * 16 + q) * 16 + r) * 8 + y] * lf[(c * 16 + r) * 8 + z];
    gs[e] = s;
  }
  __syncthreads();
  #pragma unroll
  for (int j = 0; j < 4; ++j) {
    int k = tid + j * 256;
    int p = k & 3, c = (k >> 2) & 3, b = (k >> 4) & 7, a = k >> 7;
    float s = 0.f;
    #pragma unroll
    for (int q = 0; q < 16; ++q)
      s += f0[((a * 4 + p) * 16 + q) * 8 + x] * gs[(b * 16 + q) * 4 + c];
    chainT[(size_t)o * 1024 + k] = f2bf(s);
  }
}

// ---------------- depthwise 3x3 conv -> t[m][k] bf16 (K-contiguous)
__global__ __launch_bounds__(256) void conv_kernel(const float* __restrict__ in,
                                                   const float* __restrict__ sf,
                                                   ushort_t* __restrict__ t) {
  __shared__ float in_lds[64][244];
  __shared__ float sf_l[36];
  int bid = blockIdx.x;
  int cq = bid & 3, h4 = (bid >> 2) & 7, n = bid >> 5;
  int h0 = h4 * 4;
  int tid = threadIdx.x;
  if (tid < 36) sf_l[tid] = sf[tid];
  for (int e = tid; e < 384; e += 256) {
    int ch = e / 6, r = e % 6;
    in_lds[ch][r * 40 + 3] = 0.f;
    in_lds[ch][r * 40 + 36] = 0.f;
  }
  const float* inb = in + ((size_t)n * 256 + cq * 64) * 1024;
  #pragma unroll
  for (int i = 0; i < 12; ++i) {
    int e = tid + i * 256;
    int ch = e / 48, rem = e % 48;
    int r = rem >> 3, w4 = rem & 7;
    int hh = h0 - 1 + r;
    float4 v = make_float4(0.f, 0.f, 0.f, 0.f);
    if (hh >= 0 && hh < 32)
      v = *(const float4*)&inb[(size_t)ch * 1024 + hh * 32 + w4 * 4];
    *(float4*)&in_lds[ch][r * 40 + 4 + w4 * 4] = v;
  }
  __syncthreads();
  float sfr[36];
  #pragma unroll
  for (int i = 0; i < 36; ++i) sfr[i] = sf_l[i];
  int w = tid >> 3, gg = tid & 7;
  size_t m0 = (size_t)n * 1024 + (size_t)h0 * 32 + w;
  #pragma unroll
  for (int j = 0; j < 4; ++j) {
    float acc[4][2][4];
    #pragma unroll
    for (int b = 0; b < 2; ++b) {
      int ch = j * 16 + gg * 2 + b;
      float vals[6][3];
      #pragma unroll
      for (int r = 0; r < 6; ++r)
        #pragma unroll
        for (int dw = 0; dw < 3; ++dw)
          vals[r][dw] = in_lds[ch][r * 40 + 3 + w + dw];
      #pragma unroll
      for (int hh = 0; hh < 4; ++hh)
        #pragma unroll
        for (int p = 0; p < 4; ++p) {
          float s = 0.f;
          #pragma unroll
          for (int dr = 0; dr < 3; ++dr)
            #pragma unroll
            for (int dw = 0; dw < 3; ++dw)
              s += vals[hh + dr][dw] * sfr[p * 9 + dr * 3 + dw];
          acc[hh][b][p] = s;
        }
    }
    #pragma unroll
    for (int hh = 0; hh < 4; ++hh) {
      ushort8 outv;
      #pragma unroll
      for (int b = 0; b < 2; ++b)
        #pragma unroll
        for (int p = 0; p < 4; ++p) outv[b * 4 + p] = f2bf(acc[hh][b][p]);
      *(ushort8*)&t[(m0 + hh * 32) * 1024 + (size_t)(cq * 256 + j * 64 + gg * 8)] = outv;
    }
  }
}

// ---------------- GEMM: out[m][o] = sum_k t[m][k]*chainT[o][k] + bias[o]
// BM=256, BN=128, BK=32. Triple-buffered LDS (72 KB) -> 2 blocks/CU. Grid 512.
// 8 waves (2Mx4N -> per-wave 128x32). One barrier + one counted vmcnt per kt.
// Stage is issued 2 kt ahead (buffers rotate mod 3):
//   kt: STAGE(kt+2 -> buf[(kt+2)%3]); reads+MFMA(buf[kt%3]); VMCNT3; BARRIER
// (RAW) VMCNT3 at kt-end retires exactly loads(kt+1) producer-side (6 outstanding
//       -> 3); kt=30 uses VMCNT0 (only loads(31) outstanding); kt=31 none.
// (WAR) STAGE(kt+2) overwrites the buffer last read at kt-1; those reads are all
//       consumed by same-phase MFMAs (compiler lgkmcnt) before kt-1's barrier.
#define AS1 __attribute__((address_space(1)))
#define AS3 __attribute__((address_space(3)))
#define BARRIER  __builtin_amdgcn_s_barrier()
#define VMCNT3   asm volatile("s_waitcnt vmcnt(3)" ::: "memory")
#define VMCNT0   asm volatile("s_waitcnt vmcnt(0)" ::: "memory")

__global__ __launch_bounds__(512, 4) void gemm_kernel(const ushort_t* __restrict__ tA,
                                                      const ushort_t* __restrict__ tB,
                                                      const float* __restrict__ bias,
                                                      float* __restrict__ out) {
  __shared__ __align__(16) ushort_t As[3][8192];   // 3 x 16 KB: [256 rows][32 k] swizzled
  __shared__ __align__(16) ushort_t Bs[3][4096];   // 3 x  8 KB: [128 rows][32 k] swizzled
  int tid = threadIdx.x;
  int bid = blockIdx.x;                            // 512 blocks
  int wg = (bid & 7) * 64 + (bid >> 3);            // bijective XCD swizzle (512%8==0)
  int tile_m = (wg >> 2) * 256;
  int tile_n = (wg & 3) * 128;

  int lane = tid & 63, wv = tid >> 6;
  int wm2 = (wv >> 2) * 128, wn4 = (wv & 3) * 32;  // per-wave 128M x 32N
  int lr = lane & 15, kg = lane >> 4;
  // swizzled chunk: logical chunk kg at row r lives at slot kg^(r&3); elem offset:
  int kph = ((kg ^ (lr & 3)) * 8);

  // staging: thread covers dest elems base+tid*8 (row = tid>>2, slot = tid&3);
  // source logical chunk = slot ^ (row&3), pre-applied to the global address.
  int srow = tid >> 2;                             // 0..127
  int lsw = (tid & 3) ^ (srow & 3);
  const ushort_t* sA = tA + (size_t)(tile_m + srow) * 1024 + lsw * 8;
  const ushort_t* sB = tB + (size_t)(tile_n + srow) * 1024 + lsw * 8;

#define STAGE(SB, KT)                                                                    \
  __builtin_amdgcn_global_load_lds((const AS1 void*)(sA + (KT) * 32),                    \
      (AS3 void*)&As[SB][tid * 8], 16, 0, 0);                                            \
  __builtin_amdgcn_global_load_lds((const AS1 void*)(sA + 131072 + (KT) * 32),           \
      (AS3 void*)&As[SB][4096 + tid * 8], 16, 0, 0);                                     \
  __builtin_amdgcn_global_load_lds((const AS1 void*)(sB + (KT) * 32),                    \
      (AS3 void*)&Bs[SB][tid * 8], 16, 0, 0);

#define COMPUTE(BUF)                                                                     \
  {                                                                                      \
    bf16x8 af[8], bq[2];                                                                 \
    _Pragma("unroll")                                                                    \
    for (int mf = 0; mf < 8; ++mf)                                                       \
      af[mf] = *(const bf16x8*)&As[BUF][(wm2 + mf * 16 + lr) * 32 + kph];                \
    _Pragma("unroll")                                                                    \
    for (int nf = 0; nf < 2; ++nf)                                                       \
      bq[nf] = *(const bf16x8*)&Bs[BUF][(wn4 + nf * 16 + lr) * 32 + kph];                \
    __builtin_amdgcn_s_setprio(1);                                                       \
    _Pragma("unroll")                                                                    \
    for (int mf = 0; mf < 8; ++mf)                                                       \
      _Pragma("unroll")                                                                  \
      for (int nf = 0; nf < 2; ++nf)                                                     \
        acc[mf][nf] = __builtin_amdgcn_mfma_f32_16x16x32_bf16(                           \
            af[mf], bq[nf], acc[mf][nf], 0, 0, 0);                                       \
    __builtin_amdgcn_s_setprio(0);                                                       \
  }

  f32x4 acc[8][2];
  #pragma unroll
  for (int i = 0; i < 8; ++i)
    #pragma unroll
    for (int j = 0; j < 2; ++j) acc[i][j] = (f32x4){0.f, 0.f, 0.f, 0.f};

  float bv[2];
  #pragma unroll
  for (int nf = 0; nf < 2; ++nf) bv[nf] = bias[tile_n + wn4 + nf * 16 + lr];

  // prologue: stage kt0->buf0, kt1->buf1 (6 in flight); certify kt0 pre-barrier.
  STAGE(0, 0) STAGE(1, 1)
  VMCNT3; BARRIER;

  #pragma unroll 1
  for (int I = 0; I < 10; ++I) {
    int kt = 3 * I;
    // kt (buf0): stage kt+2 -> buf2
    STAGE(2, kt + 2)
    COMPUTE(0)
    VMCNT3; BARRIER;
    // kt+1 (buf1): stage kt+3 -> buf0
    STAGE(0, kt + 3)
    COMPUTE(1)
    VMCNT3; BARRIER;
    // kt+2 (buf2): stage kt+4 -> buf1
    STAGE(1, kt + 4)
    COMPUTE(2)
    VMCNT3; BARRIER;
  }
  // kt=30 (buf0): no stage; certify loads(31) fully.
  COMPUTE(0)
  VMCNT0; BARRIER;
  // kt=31 (buf1): no stage, no waits needed after.
  COMPUTE(1)

  // epilogue: lane holds D[m=kg*4+r][o=lr] per 16x16 frag
  #pragma unroll
  for (int mf = 0; mf < 8; ++mf)
    #pragma unroll
    for (int nf = 0; nf < 2; ++nf) {
      int m = tile_m + wm2 + mf * 16 + kg * 4;
      int o = tile_n + wn4 + nf * 16 + lr;
      f32x4 v = acc[mf][nf];
      v[0] += bv[nf]; v[1] += bv[nf]; v[2] += bv[nf]; v[3] += bv[nf];
      *(f32x4*)&out[(size_t)(m >> 10) * 524288 + (size_t)o * 1024 + (size_t)(m & 1023)] = v;
    }
}

extern "C" void kernel_launch(void* const* d_in, const int* in_sizes, int n_in,
                              void* d_out, int out_size, void* d_ws, size_t ws_size,
                              hipStream_t stream) {
  (void)in_sizes; (void)n_in; (void)out_size; (void)ws_size;
  const float* in   = (const float*)d_in[0];
  const float* sf   = (const float*)d_in[1];
  const float* f0   = (const float*)d_in[2];
  const float* f1   = (const float*)d_in[3];
  const float* lf   = (const float*)d_in[4];
  const float* bias = (const float*)d_in[5];
  float* out = (float*)d_out;

  char* ws = (char*)d_ws;
  ushort_t* t      = (ushort_t*)ws;                          // 64 MB
  ushort_t* chainT = (ushort_t*)(ws + 67108864);             // 1 MB

  hipLaunchKernelGGL(chain_kernel, dim3(512),  dim3(256), 0, stream, f0, f1, lf, chainT);
  hipLaunchKernelGGL(conv_kernel,  dim3(1024), dim3(256), 0, stream, in, sf, t);
  hipLaunchKernelGGL(gemm_kernel,  dim3(512),  dim3(512), 0, stream, t, chainT, bias, out);
}

// Round 16
// 71.001 us; speedup vs baseline: 1.1392x; 1.1392x over previous
//
#include <hip/hip_runtime.h>

typedef unsigned short ushort_t;
typedef __attribute__((ext_vector_type(8))) short bf16x8;
typedef __attribute__((ext_vector_type(8))) unsigned short ushort8;
typedef __attribute__((ext_vector_type(4))) float f32x4;

__device__ __forceinline__ unsigned short f2bf(float f) {
  union { float f; unsigned u; } x; x.f = f;
  unsigned r = x.u + 0x7FFFu + ((x.u >> 16) & 1u);   // round-to-nearest-even
  return (unsigned short)(r >> 16);
}

// ---------------- fused chain: block = one o (512 blocks x 256 thr)
__global__ __launch_bounds__(256) void chain_kernel(const float* __restrict__ f0,
                                                    const float* __restrict__ f1,
                                                    const float* __restrict__ lf,
                                                    ushort_t* __restrict__ chainT) {
  __shared__ float gs[512];
  int o = blockIdx.x;
  int z = o & 7, y = (o >> 3) & 7, x = o >> 6;
  int tid = threadIdx.x;
  #pragma unroll
  for (int i = 0; i < 2; ++i) {
    int e = tid + i * 256;                 // (b*16+q)*4+c
    int c = e & 3, q = (e >> 2) & 15, b = e >> 6;
    float s = 0.f;
    #pragma unroll
    for (int r = 0; r < 16; ++r)
      s += f1[((b * 16 + q) * 16 + r) * 8 + y] * lf[(c * 16 + r) * 8 + z];
    gs[e] = s;
  }
  __syncthreads();
  #pragma unroll
  for (int j = 0; j < 4; ++j) {
    int k = tid + j * 256;
    int p = k & 3, c = (k >> 2) & 3, b = (k >> 4) & 7, a = k >> 7;
    float s = 0.f;
    #pragma unroll
    for (int q = 0; q < 16; ++q)
      s += f0[((a * 4 + p) * 16 + q) * 8 + x] * gs[(b * 16 + q) * 4 + c];
    chainT[(size_t)o * 1024 + k] = f2bf(s);
  }
}

// ---------------- depthwise 3x3 conv -> t[m][k] bf16 (K-contiguous)
// block = (n, h-oct: 8 out rows, 16-channel group). grid = 32*4*16 = 2048.
// LDS 25.9 KB -> 6 blocks/CU; halo amp = 10/8 = 1.25x.
__global__ __launch_bounds__(256) void conv_kernel(const float* __restrict__ in,
                                                   const float* __restrict__ sf,
                                                   ushort_t* __restrict__ t) {
  __shared__ float in_lds[16][404];    // 16 ch x (10 rows * 40 + 4 pad)
  __shared__ float sf_l[36];
  int bid = blockIdx.x;
  int cg = bid & 15, hg = (bid >> 4) & 3, n = bid >> 6;
  int h0 = hg * 8;                     // out rows h0..h0+7; in rows h0-1..h0+8
  int tid = threadIdx.x;
  if (tid < 36) sf_l[tid] = sf[tid];
  // zero halo columns: 16 ch x 10 r x {col 3, col 36}
  for (int e = tid; e < 320; e += 256) {
    int ch = e / 20, rr = e % 20;
    in_lds[ch][(rr >> 1) * 40 + 3 + (rr & 1) * 33] = 0.f;
  }
  // load 16 ch x 10 rows x 32 w as float4 (1280 float4, 5 per thread)
  const float* inb = in + ((size_t)n * 256 + cg * 16) * 1024;
  #pragma unroll
  for (int i = 0; i < 5; ++i) {
    int e = tid + i * 256;             // 0..1279
    int ch = e / 80, rem = e % 80;
    int r = rem >> 3, w4 = rem & 7;
    int hh = h0 - 1 + r;
    float4 v = make_float4(0.f, 0.f, 0.f, 0.f);
    if (hh >= 0 && hh < 32)
      v = *(const float4*)&inb[(size_t)ch * 1024 + hh * 32 + w4 * 4];
    *(float4*)&in_lds[ch][r * 40 + 4 + w4 * 4] = v;
  }
  __syncthreads();
  float sfr[36];
  #pragma unroll
  for (int i = 0; i < 36; ++i) sfr[i] = sf_l[i];
  int w = tid & 31, sub = tid >> 5;    // w:0..31  sub:0..7 -> channels sub*2, sub*2+1
  size_t m0 = (size_t)n * 1024 + (size_t)h0 * 32 + w;
  unsigned pw[8][4];                   // [out row][b*2 + hi/lo packed bf16 pair]
  #pragma unroll
  for (int b = 0; b < 2; ++b) {
    int ch = sub * 2 + b;
    float vals[10][3];
    #pragma unroll
    for (int r = 0; r < 10; ++r)
      #pragma unroll
      for (int dw = 0; dw < 3; ++dw)
        vals[r][dw] = in_lds[ch][r * 40 + 3 + w + dw];
    #pragma unroll
    for (int j = 0; j < 8; ++j) {
      float s0 = 0.f, s1 = 0.f, s2 = 0.f, s3 = 0.f;
      #pragma unroll
      for (int dr = 0; dr < 3; ++dr)
        #pragma unroll
        for (int dw = 0; dw < 3; ++dw) {
          float tv = vals[j + dr][dw];
          s0 += tv * sfr[0 * 9 + dr * 3 + dw];
          s1 += tv * sfr[1 * 9 + dr * 3 + dw];
          s2 += tv * sfr[2 * 9 + dr * 3 + dw];
          s3 += tv * sfr[3 * 9 + dr * 3 + dw];
        }
      pw[j][b * 2 + 0] = (unsigned)f2bf(s0) | ((unsigned)f2bf(s1) << 16);
      pw[j][b * 2 + 1] = (unsigned)f2bf(s2) | ((unsigned)f2bf(s3) << 16);
    }
  }
  #pragma unroll
  for (int j = 0; j < 8; ++j) {
    uint4 pk; pk.x = pw[j][0]; pk.y = pw[j][1]; pk.z = pw[j][2]; pk.w = pw[j][3];
    // k = (cg*16 + sub*2)*4 : sub 0..7 contiguous 16B chunks within the 128B k-row
    *(uint4*)&t[(m0 + (size_t)j * 32) * 1024 + (size_t)(cg * 64 + sub * 8)] = pk;
  }
}

// ---------------- GEMM: out[m][o] = sum_k t[m][k]*chainT[o][k] + bias[o]
// (verbatim round-14: 256x256, BK=64, 8 waves, 8 single-barrier phases,
//  producer-side counted vmcnt, XOR-swizzle, sound WAR/RAW rules.)
#define AS1 __attribute__((address_space(1)))
#define AS3 __attribute__((address_space(3)))
#define BARRIER  __builtin_amdgcn_s_barrier()
#define LGKMCNT0 asm volatile("s_waitcnt lgkmcnt(0)" ::: "memory")
#define VMCNT4   asm volatile("s_waitcnt vmcnt(4)" ::: "memory")
#define VMCNT0   asm volatile("s_waitcnt vmcnt(0)" ::: "memory")

__global__ __launch_bounds__(512, 2) void gemm_kernel(const ushort_t* __restrict__ tA,
                                                      const ushort_t* __restrict__ tB,
                                                      const float* __restrict__ bias,
                                                      float* __restrict__ out) {
  __shared__ __align__(16) ushort_t smem[65536];   // 128 KB: As[2][16384] | Bs[2][16384]
  int tid = threadIdx.x;
  int bid = blockIdx.x;                            // 256 blocks
  int wg = (bid & 7) * 32 + (bid >> 3);            // bijective XCD swizzle (256%8==0)
  int tile_m = (wg >> 1) * 256;
  int tile_n = (wg & 1) * 256;

  int lane = tid & 63, wv = tid >> 6;
  int wm2 = wv >> 2, wn4 = wv & 3;
  int lr = lane & 15, kg = lane >> 4;
  int kph0 = ((kg * 8) ^ ((lane & 7) * 8));
  int kph1 = ((32 + kg * 8) ^ ((lane & 7) * 8));
  int arow = wm2 * 128 + lr;
  int brow = wn4 * 64 + lr;

  int srow = tid >> 3;
  int scol = ((tid & 7) ^ (srow & 7)) * 8;
  const ushort_t* sA = tA + (size_t)(tile_m + srow) * 1024 + scol;
  const ushort_t* sB = tB + (size_t)(tile_n + srow) * 1024 + scol;

#define STAGE_A(buf, koff, h)                                                                  \
  __builtin_amdgcn_global_load_lds((const AS1 void*)(sA + (size_t)((h)*128) * 1024 + (koff)),  \
      (AS3 void*)&smem[(buf)*16384 + (h)*8192 + tid*8], 16, 0, 0);                             \
  __builtin_amdgcn_global_load_lds((const AS1 void*)(sA + (size_t)((h)*128+64) * 1024 + (koff)),\
      (AS3 void*)&smem[(buf)*16384 + (h)*8192 + 4096 + tid*8], 16, 0, 0);
#define STAGE_B(buf, koff, h)                                                                  \
  __builtin_amdgcn_global_load_lds((const AS1 void*)(sB + (size_t)((h)*128) * 1024 + (koff)),  \
      (AS3 void*)&smem[32768 + (buf)*16384 + (h)*8192 + tid*8], 16, 0, 0);                     \
  __builtin_amdgcn_global_load_lds((const AS1 void*)(sB + (size_t)((h)*128+64) * 1024 + (koff)),\
      (AS3 void*)&smem[32768 + (buf)*16384 + (h)*8192 + 4096 + tid*8], 16, 0, 0);

#define READ_A(dst, mbase, buf)                                                                \
  _Pragma("unroll")                                                                            \
  for (int mf = 0; mf < 4; ++mf) {                                                             \
    dst[mf][0] = *(const bf16x8*)&smem[(buf)*16384 + (arow + (mbase) + mf*16)*64 + kph0];      \
    dst[mf][1] = *(const bf16x8*)&smem[(buf)*16384 + (arow + (mbase) + mf*16)*64 + kph1];      \
  }
#define READ_B(dst, nbase, buf)                                                                \
  _Pragma("unroll")                                                                            \
  for (int nf = 0; nf < 2; ++nf) {                                                             \
    dst[nf][0] = *(const bf16x8*)&smem[32768 + (buf)*16384 + (brow + (nbase) + nf*16)*64 + kph0];\
    dst[nf][1] = *(const bf16x8*)&smem[32768 + (buf)*16384 + (brow + (nbase) + nf*16)*64 + kph1];\
  }
#define Q_MFMA(AF, BF, MB, NB)                                                                 \
  __builtin_amdgcn_s_setprio(1);                                                              \
  _Pragma("unroll")                                                                            \
  for (int mf = 0; mf < 4; ++mf)                                                               \
    _Pragma("unroll")                                                                          \
    for (int nf = 0; nf < 2; ++nf)                                                             \
      _Pragma("unroll")                                                                        \
      for (int ks = 0; ks < 2; ++ks)                                                           \
        acc[(MB) + mf][(NB) + nf] = __builtin_amdgcn_mfma_f32_16x16x32_bf16(                   \
            AF[mf][ks], BF[nf][ks], acc[(MB) + mf][(NB) + nf], 0, 0, 0);                       \
  __builtin_amdgcn_s_setprio(0);

  f32x4 acc[8][4];
  #pragma unroll
  for (int i = 0; i < 8; ++i)
    #pragma unroll
    for (int j = 0; j < 4; ++j) acc[i][j] = (f32x4){0.f, 0.f, 0.f, 0.f};

  bf16x8 a1[4][2], a2[4][2], b1[2][2], b2[2][2];

  STAGE_A(0, 0, 0) STAGE_A(0, 0, 1) STAGE_B(0, 0, 0) STAGE_B(0, 0, 1)
  STAGE_A(1, 64, 0) STAGE_A(1, 64, 1)
  VMCNT4; BARRIER;

#define ITER(I_, FULL)                                                                         \
  {                                                                                            \
    int k1 = (2*(I_)+1)*64, k2 = (2*(I_)+2)*64, k3 = (2*(I_)+3)*64;                            \
    READ_A(a1, 0, 0) READ_B(b1, 0, 0)                                                          \
    STAGE_B(1, k1, 0)                                                                          \
    Q_MFMA(a1, b1, 0, 0) BARRIER;                                                              \
    READ_B(b2, 32, 0) READ_A(a2, 64, 0)                                                        \
    STAGE_B(1, k1, 1)                                                                          \
    Q_MFMA(a1, b2, 0, 2) LGKMCNT0; BARRIER;                                                    \
    if (FULL) { STAGE_A(0, k2, 0) }                                                            \
    Q_MFMA(a2, b2, 4, 2) BARRIER;                                                              \
    if (FULL) { STAGE_A(0, k2, 1) }                                                            \
    Q_MFMA(a2, b1, 4, 0)                                                                       \
    if (FULL) { VMCNT4; } else { VMCNT0; }                                                     \
    BARRIER;                                                                                   \
    READ_A(a1, 0, 1) READ_B(b1, 0, 1)                                                          \
    if (FULL) { STAGE_B(0, k2, 0) }                                                            \
    Q_MFMA(a1, b1, 0, 0) BARRIER;                                                              \
    READ_B(b2, 32, 1) READ_A(a2, 64, 1)                                                        \
    if (FULL) { STAGE_B(0, k2, 1) }                                                            \
    Q_MFMA(a1, b2, 0, 2) LGKMCNT0; BARRIER;                                                    \
    if (FULL) { STAGE_A(1, k3, 0) }                                                            \
    Q_MFMA(a2, b2, 4, 2) BARRIER;                                                              \
    if (FULL) { STAGE_A(1, k3, 1) }                                                            \
    Q_MFMA(a2, b1, 4, 0)                                                                       \
    if (FULL) { VMCNT4; }                                                                      \
    BARRIER;                                                                                   \
  }

  for (int I = 0; I < 7; ++I) ITER(I, 1)
  ITER(7, 0)
#undef ITER

  #pragma unroll
  for (int mf = 0; mf < 8; ++mf)
    #pragma unroll
    for (int nf = 0; nf < 4; ++nf) {
      int m = tile_m + wm2 * 128 + mf * 16 + kg * 4;
      int o = tile_n + wn4 * 64 + nf * 16 + lr;
      float bv = bias[o];
      f32x4 v = acc[mf][nf];
      v[0] += bv; v[1] += bv; v[2] += bv; v[3] += bv;
      *(f32x4*)&out[(size_t)(m >> 10) * 524288 + (size_t)o * 1024 + (size_t)(m & 1023)] = v;
    }
}

extern "C" void kernel_launch(void* const* d_in, const int* in_sizes, int n_in,
                              void* d_out, int out_size, void* d_ws, size_t ws_size,
                              hipStream_t stream) {
  (void)in_sizes; (void)n_in; (void)out_size; (void)ws_size;
  const float* in   = (const float*)d_in[0];
  const float* sf   = (const float*)d_in[1];
  const float* f0   = (const float*)d_in[2];
  const float* f1   = (const float*)d_in[3];
  const float* lf   = (const float*)d_in[4];
  const float* bias = (const float*)d_in[5];
  float* out = (float*)d_out;

  char* ws = (char*)d_ws;
  ushort_t* t      = (ushort_t*)ws;                          // 64 MB
  ushort_t* chainT = (ushort_t*)(ws + 67108864);             // 1 MB

  hipLaunchKernelGGL(chain_kernel, dim3(512),  dim3(256), 0, stream, f0, f1, lf, chainT);
  hipLaunchKernelGGL(conv_kernel,  dim3(2048), dim3(256), 0, stream, in, sf, t);
  hipLaunchKernelGGL(gemm_kernel,  dim3(256),  dim3(512), 0, stream, t, chainT, bias, out);
}